// Round 3
// baseline (3977.541 us; speedup 1.0000x reference)
//
#include <hip/hip_runtime.h>
#include <cstddef>

#define B_ 32
#define T_ 1024
#define IN_ 256
#define H_ 512
#define O_ 256
#define DT_ 0.1f

typedef _Float16 half2_t __attribute__((ext_vector_type(2)));

__device__ __forceinline__ float fdot2(half2_t a, half2_t b, float c) {
#if defined(__has_builtin)
#if __has_builtin(__builtin_amdgcn_fdot2)
    return __builtin_amdgcn_fdot2(a, b, c, false);
#else
    return c + (float)a[0] * (float)b[0] + (float)a[1] * (float)b[1];
#endif
#else
    return c + (float)a[0] * (float)b[0] + (float)a[1] * (float)b[1];
#endif
}

__device__ __forceinline__ half2_t cvt2(float x, float y) {
    half2_t r; r[0] = (_Float16)x; r[1] = (_Float16)y; return r;
}

__device__ __forceinline__ half2_t as_h2(float f) {
    union { float f; half2_t h; } u; u.f = f; return u.h;
}

// ---------------------------------------------------------------------------
// Generic fp32 GEMM: C[m][n] = sum_k A[m][k] * Bw[n][k],  M = 32768 fixed.
// Row index m = t*32 + b.  SWA/SWC remap the A/C row to (b*T + t) layout.
// ---------------------------------------------------------------------------
template<int N, int K, bool SWA, bool SWC>
__global__ __launch_bounds__(256, 4) void gemm128(const float* __restrict__ A,
                                                  const float* __restrict__ Bw,
                                                  float* __restrict__ C) {
    __shared__ float al[32][132];
    __shared__ float bl[32][132];
    const int tid = threadIdx.x;
    const int m0 = blockIdx.x * 128;
    const int n0 = blockIdx.y * 128;
    const int tx = tid & 15;
    const int ty = tid >> 4;
    float acc[8][8] = {};

    const int lrow = tid >> 3;
    const int kk = (tid & 7) * 4;

    for (int kc = 0; kc < K; kc += 32) {
        __syncthreads();
#pragma unroll
        for (int p = 0; p < 4; ++p) {
            const int row = lrow + p * 32;
            const int m = m0 + row;
            const size_t aoff = SWA ? ((size_t)((m & 31) * T_ + (m >> 5)) * K)
                                    : ((size_t)m * K);
            const float4 v = *(const float4*)(A + aoff + kc + kk);
            al[kk + 0][row] = v.x; al[kk + 1][row] = v.y;
            al[kk + 2][row] = v.z; al[kk + 3][row] = v.w;
        }
#pragma unroll
        for (int p = 0; p < 4; ++p) {
            const int row = lrow + p * 32;
            const float4 v = *(const float4*)(Bw + (size_t)(n0 + row) * K + kc + kk);
            bl[kk + 0][row] = v.x; bl[kk + 1][row] = v.y;
            bl[kk + 2][row] = v.z; bl[kk + 3][row] = v.w;
        }
        __syncthreads();
#pragma unroll
        for (int k = 0; k < 32; ++k) {
            float av[8], bv[8];
            *(float4*)&av[0] = *(const float4*)&al[k][ty * 8];
            *(float4*)&av[4] = *(const float4*)&al[k][ty * 8 + 4];
            *(float4*)&bv[0] = *(const float4*)&bl[k][tx * 8];
            *(float4*)&bv[4] = *(const float4*)&bl[k][tx * 8 + 4];
#pragma unroll
            for (int i = 0; i < 8; ++i)
#pragma unroll
                for (int j = 0; j < 8; ++j)
                    acc[i][j] = fmaf(av[i], bv[j], acc[i][j]);
        }
    }
#pragma unroll
    for (int i = 0; i < 8; ++i) {
        const int m = m0 + ty * 8 + i;
        const size_t coff = SWC ? ((size_t)((m & 31) * T_ + (m >> 5)) * N)
                                : ((size_t)m * N);
        const float4 v0 = make_float4(acc[i][0], acc[i][1], acc[i][2], acc[i][3]);
        const float4 v1 = make_float4(acc[i][4], acc[i][5], acc[i][6], acc[i][7]);
        *(float4*)(C + coff + n0 + tx * 8) = v0;
        *(float4*)(C + coff + n0 + tx * 8 + 4) = v1;
    }
}

// ---------------------------------------------------------------------------
// K2: a_coef[t][h] = 1 - DT / softplus(tc[h] + 0.1 * mean_b |sensory[t][b][h]|)
// ---------------------------------------------------------------------------
__global__ __launch_bounds__(512) void tau_kernel(const float* __restrict__ sens,
                                                  const float* __restrict__ tc,
                                                  float* __restrict__ acoef) {
    const int t = blockIdx.x;
    const int h = threadIdx.x;
    float s = 0.f;
#pragma unroll 8
    for (int b = 0; b < B_; ++b)
        s += fabsf(sens[((size_t)t * B_ + b) * H_ + h]);
    const float x = tc[h] + 0.1f * (s * (1.f / 32.f));
    const float sp = fmaxf(x, 0.f) + log1pf(expf(-fabsf(x)));  // stable softplus
    acoef[(size_t)t * H_ + h] = 1.f - DT_ / sp;
}

// ---------------------------------------------------------------------------
// K3: serial scan. 32 WGs (1 per batch) x 1024 threads (16 waves, 4/SIMD).
// Thread (c = tid>>7, rg = tid&127): rows 4rg..+3, cols 64c..+63.
// W slice = 4x64 f16 = 128 half2 -> ENTIRELY in VGPRs (<= 256 arch cap;
// amdgpu_waves_per_eu(4,4) gives the allocator a 512-reg budget so it has
// no occupancy incentive to demote to AGPR/scratch).
// Per step LDS: 8 uniform b128 h-broadcast reads/thread, 1 b128 pred write,
// 8 b32 pred reads (2-way bank alias, free) in the update half-wave.
// 96 KB dynamic LDS forces 1 WG/CU (prevents 2 batches sharing a CU's VALU).
// ---------------------------------------------------------------------------
#define SMEM_P   16384                     // pred [8][512] f32
#define SMEM_TOT 98304                     // oversized to force 1 WG/CU

__global__ __attribute__((amdgpu_flat_work_group_size(1024, 1024),
                          amdgpu_waves_per_eu(4, 4)))
void scan_kernel(const float* __restrict__ Wr, const float* __restrict__ acoef,
                 const float* __restrict__ bias, float* sensH,
                 float* __restrict__ finalh) {
    extern __shared__ char smem[];
    float* pred   = (float*)smem;                  // [8][512]
    _Float16* h2s = (_Float16*)(smem + SMEM_P);    // [512]

    const int tid = threadIdx.x;
    const int b = blockIdx.x;
    const int c = tid >> 7;        // col chunk 0..7 (64 cols)
    const int rg = tid & 127;      // row group 0..127
    const int row0 = rg * 4;
    const int col0 = c * 64;

    // --- one-time: load + convert this thread's W_r slice (128 half2) ---
    half2_t wr[4][32];
#pragma unroll
    for (int r = 0; r < 4; ++r) {
        const float* wrow = Wr + (size_t)(row0 + r) * H_ + col0;
#pragma unroll
        for (int d = 0; d < 16; ++d) {
            const float4 v = *(const float4*)(wrow + 4 * d);
            wr[r][2 * d + 0] = cvt2(v.x, v.y);
            wr[r][2 * d + 1] = cvt2(v.z, v.w);
        }
    }

    float h_reg = 0.f, s_cur = 0.f, a_cur = 0.f, bias_r = 0.f;
    if (tid < 256) ((half2_t*)h2s)[tid] = cvt2(0.f, 0.f);
    if (tid < H_) {
        bias_r = bias[tid];
        s_cur = sensH[(size_t)b * H_ + tid];        // sensory[t=0][b][tid]
        a_cur = acoef[tid];
    }
    __syncthreads();

    const half2_t* h2c = (const half2_t*)h2s + c * 32;   // wave-uniform base

    for (int t = 0; t < T_; ++t) {
        float s_nxt = 0.f, a_nxt = 0.f;
        if (tid < H_) {
            const int tn = (t < T_ - 1) ? t + 1 : t;
            s_nxt = sensH[((size_t)tn * B_ + b) * H_ + tid];
            a_nxt = acoef[(size_t)tn * H_ + tid];
        }

        // two accumulators per row to shorten the dot2 dependency chain
        float acc0[4] = {0.f, 0.f, 0.f, 0.f};
        float acc1[4] = {0.f, 0.f, 0.f, 0.f};
#pragma unroll
        for (int g = 0; g < 8; ++g) {
            const float4 hv = *(const float4*)(h2c + g * 4);   // uniform b128
            const half2_t hh[4] = {as_h2(hv.x), as_h2(hv.y), as_h2(hv.z), as_h2(hv.w)};
#pragma unroll
            for (int r = 0; r < 4; ++r) {
                acc0[r] = fdot2(wr[r][g * 4 + 0], hh[0], acc0[r]);
                acc1[r] = fdot2(wr[r][g * 4 + 1], hh[1], acc1[r]);
                acc0[r] = fdot2(wr[r][g * 4 + 2], hh[2], acc0[r]);
                acc1[r] = fdot2(wr[r][g * 4 + 3], hh[3], acc1[r]);
            }
        }
        *(float4*)(pred + c * 512 + row0) =
            make_float4(acc0[0] + acc1[0], acc0[1] + acc1[1],
                        acc0[2] + acc1[2], acc0[3] + acc1[3]);
        __syncthreads();

        if (tid < H_) {
            float rec = 0.f;
#pragma unroll
            for (int cc = 0; cc < 8; ++cc) rec += pred[cc * 512 + tid];
            const float act = tanhf(s_cur + rec + bias_r);
            h_reg = a_cur * h_reg + DT_ * act;
            sensH[((size_t)t * B_ + b) * H_ + tid] = h_reg;   // hiddens overwrite sensory
            h2s[tid] = (_Float16)h_reg;
            s_cur = s_nxt;
            a_cur = a_nxt;
        }
        __syncthreads();
    }
    if (tid < H_) finalh[(size_t)b * H_ + tid] = h_reg;
}

// ---------------------------------------------------------------------------
extern "C" void kernel_launch(void* const* d_in, const int* in_sizes, int n_in,
                              void* d_out, int out_size, void* d_ws, size_t ws_size,
                              hipStream_t stream) {
    const float* x    = (const float*)d_in[0];
    const float* Win  = (const float*)d_in[1];
    const float* Wr   = (const float*)d_in[2];
    const float* tc   = (const float*)d_in[3];
    const float* Wo   = (const float*)d_in[4];
    const float* bias = (const float*)d_in[5];
    float* out = (float*)d_out;

    float* sensH = (float*)d_ws;                               // [T*B][H], later hiddens
    float* acoef = sensH + (size_t)T_ * B_ * H_;               // [T][H]
    const size_t need = ((size_t)T_ * B_ * H_ + (size_t)T_ * H_) * sizeof(float);
    if (ws_size < need) return;

    (void)hipFuncSetAttribute((const void*)scan_kernel,
                              hipFuncAttributeMaxDynamicSharedMemorySize, SMEM_TOT);

    // K1: sensory[t*32+b][h] = sum_i x[b][t][i] * Win[h][i]
    {
        dim3 grid(32768 / 128, H_ / 128);
        hipLaunchKernelGGL((gemm128<H_, IN_, true, false>), grid, dim3(256), 0, stream,
                           x, Win, sensH);
    }
    // K2: a_coef
    hipLaunchKernelGGL(tau_kernel, dim3(T_), dim3(H_), 0, stream, sensH, tc, acoef);
    // K3: scan (writes hiddens into sensH, final hidden into d_out tail)
    hipLaunchKernelGGL(scan_kernel, dim3(B_), dim3(1024), SMEM_TOT, stream,
                       Wr, acoef, bias, sensH, out + (size_t)B_ * T_ * O_);
    // K4: out[b][t][o] = sum_h hiddens[t*32+b][h] * Wo[o][h]
    {
        dim3 grid(32768 / 128, O_ / 128);
        hipLaunchKernelGGL((gemm128<O_, H_, false, true>), grid, dim3(256), 0, stream,
                           sensH, Wo, out);
    }
}

// Round 5
// 1891.268 us; speedup vs baseline: 2.1031x; 2.1031x over previous
//
#include <hip/hip_runtime.h>
#include <cstddef>
#include <cstdint>

#define B_ 32
#define T_ 1024
#define IN_ 256
#define H_ 512
#define O_ 256
#define DT_ 0.1f

typedef _Float16 half2_t __attribute__((ext_vector_type(2)));
typedef int v16i __attribute__((ext_vector_type(16)));

__device__ __forceinline__ half2_t cvt2(float x, float y) {
    half2_t r; r[0] = (_Float16)x; r[1] = (_Float16)y; return r;
}
__device__ __forceinline__ half2_t as_h2(float f) {
    union { float f; half2_t h; } u; u.f = f; return u.h;
}

// ---------------------------------------------------------------------------
// Generic fp32 GEMM: C[m][n] = sum_k A[m][k] * Bw[n][k],  M = 32768 fixed.
// ---------------------------------------------------------------------------
template<int N, int K, bool SWA, bool SWC>
__global__ __launch_bounds__(256, 4) void gemm128(const float* __restrict__ A,
                                                  const float* __restrict__ Bw,
                                                  float* __restrict__ C) {
    __shared__ float al[32][132];
    __shared__ float bl[32][132];
    const int tid = threadIdx.x;
    const int m0 = blockIdx.x * 128;
    const int n0 = blockIdx.y * 128;
    const int tx = tid & 15;
    const int ty = tid >> 4;
    float acc[8][8] = {};

    const int lrow = tid >> 3;
    const int kk = (tid & 7) * 4;

    for (int kc = 0; kc < K; kc += 32) {
        __syncthreads();
#pragma unroll
        for (int p = 0; p < 4; ++p) {
            const int row = lrow + p * 32;
            const int m = m0 + row;
            const size_t aoff = SWA ? ((size_t)((m & 31) * T_ + (m >> 5)) * K)
                                    : ((size_t)m * K);
            const float4 v = *(const float4*)(A + aoff + kc + kk);
            al[kk + 0][row] = v.x; al[kk + 1][row] = v.y;
            al[kk + 2][row] = v.z; al[kk + 3][row] = v.w;
        }
#pragma unroll
        for (int p = 0; p < 4; ++p) {
            const int row = lrow + p * 32;
            const float4 v = *(const float4*)(Bw + (size_t)(n0 + row) * K + kc + kk);
            bl[kk + 0][row] = v.x; bl[kk + 1][row] = v.y;
            bl[kk + 2][row] = v.z; bl[kk + 3][row] = v.w;
        }
        __syncthreads();
#pragma unroll
        for (int k = 0; k < 32; ++k) {
            float av[8], bv[8];
            *(float4*)&av[0] = *(const float4*)&al[k][ty * 8];
            *(float4*)&av[4] = *(const float4*)&al[k][ty * 8 + 4];
            *(float4*)&bv[0] = *(const float4*)&bl[k][tx * 8];
            *(float4*)&bv[4] = *(const float4*)&bl[k][tx * 8 + 4];
#pragma unroll
            for (int i = 0; i < 8; ++i)
#pragma unroll
                for (int j = 0; j < 8; ++j)
                    acc[i][j] = fmaf(av[i], bv[j], acc[i][j]);
        }
    }
#pragma unroll
    for (int i = 0; i < 8; ++i) {
        const int m = m0 + ty * 8 + i;
        const size_t coff = SWC ? ((size_t)((m & 31) * T_ + (m >> 5)) * N)
                                : ((size_t)m * N);
        const float4 v0 = make_float4(acc[i][0], acc[i][1], acc[i][2], acc[i][3]);
        const float4 v1 = make_float4(acc[i][4], acc[i][5], acc[i][6], acc[i][7]);
        *(float4*)(C + coff + n0 + tx * 8) = v0;
        *(float4*)(C + coff + n0 + tx * 8 + 4) = v1;
    }
}

// ---------------------------------------------------------------------------
// K2: a_coef[t][h] = 1 - DT / softplus(tc[h] + 0.1 * mean_b |sensory[t][b][h]|)
// ---------------------------------------------------------------------------
__global__ __launch_bounds__(512) void tau_kernel(const float* __restrict__ sens,
                                                  const float* __restrict__ tc,
                                                  float* __restrict__ acoef) {
    const int t = blockIdx.x;
    const int h = threadIdx.x;
    float s = 0.f;
#pragma unroll 8
    for (int b = 0; b < B_; ++b)
        s += fabsf(sens[((size_t)t * B_ + b) * H_ + h]);
    const float x = tc[h] + 0.1f * (s * (1.f / 32.f));
    const float sp = fmaxf(x, 0.f) + log1pf(expf(-fabsf(x)));
    acoef[(size_t)t * H_ + h] = 1.f - DT_ / sp;
}

// ---------------------------------------------------------------------------
// K3: serial scan. 32 WGs (1/batch) x 512 threads (8 waves, 2/SIMD).
// Wave w: col-chunk cw = w&3 (128 cols), row-half rh = w>>2.
// Lane: rows rh*256 + lane*4 .. +3.
//   per row: 48 half2 (cols 0..95 of chunk) in VGPRs (192 total, <=256 cap)
//            16 half2 (cols 96..127) in LDS (4 x b128 per row per step)
// h[512] f16 lives in GLOBAL (d_out scratch head, L2-resident); each wave
// s_loads its 256-B slice into 64 SGPRs per step (scalar pipe, off the LDS
// pipe). Base pointer hoisted to SGPR via readfirstlane (wave-uniform).
// Coherence: vector h-stores drained by __syncthreads' vmcnt(0); s_dcache_inv
// then forces s_load to re-fetch from L2. pred[4][512] LDS reduction.
// ---------------------------------------------------------------------------
#define LDSW_BYTES (16 * 512 * 16)                    // 131072
#define SMEM_TOT   (LDSW_BYTES + 4 * 512 * 4)         // + pred = 139264

#define DOT2SV(acc, hs, wv) \
    asm("v_dot2_f32_f16 %0, %1, %2, %0" : "+v"(acc) : "s"(hs), "v"(wv))

#define HV(k) ((k) < 16 ? h0[(k)] : (k) < 32 ? h1[(k) - 16] : \
               (k) < 48 ? h2[(k) - 32] : h3[(k) - 48])

__global__ __attribute__((amdgpu_flat_work_group_size(512, 512),
                          amdgpu_waves_per_eu(2, 2)))
void scan_kernel(const float* __restrict__ Wr, const float* __restrict__ acoef,
                 const float* __restrict__ bias, float* sensH,
                 float* __restrict__ finalh, _Float16* __restrict__ h2g) {
    extern __shared__ char smem[];
    half2_t* wl = (half2_t*)smem;                    // [(r*4+pp)*512+tid]*4+j
    float* pred = (float*)(smem + LDSW_BYTES);       // [4][512]

    const int tid  = threadIdx.x;
    const int b    = blockIdx.x;
    const int lane = tid & 63;
    const int w    = tid >> 6;
    const int cw   = w & 3;
    const int rh   = w >> 2;
    const int row0 = rh * 256 + lane * 4;
    const int col0 = cw * 128;

    // --- one-time: W slice -> 192 VGPR half2 + 64 LDS half2 per lane ---
    half2_t wr[4][48];
#pragma unroll
    for (int r = 0; r < 4; ++r) {
        const float* wrow = Wr + (size_t)(row0 + r) * H_ + col0;
#pragma unroll
        for (int k = 0; k < 48; ++k) {
            const float2 v = *(const float2*)(wrow + 2 * k);
            wr[r][k] = cvt2(v.x, v.y);
        }
#pragma unroll
        for (int pp = 0; pp < 4; ++pp)
#pragma unroll
            for (int j = 0; j < 4; ++j) {
                const int k = 48 + pp * 4 + j;
                const float2 v = *(const float2*)(wrow + 2 * k);
                wl[((size_t)(r * 4 + pp) * 512 + tid) * 4 + j] = cvt2(v.x, v.y);
            }
    }

    // init this batch's h (f16, global scratch) to zero
    if (tid < 256) ((half2_t*)(h2g + (size_t)b * H_))[tid] = cvt2(0.f, 0.f);

    float h_reg = 0.f;
    const float bias_r = bias[tid];
    float s_cur = sensH[(size_t)b * H_ + tid];
    float a_cur = acoef[tid];

    // wave-uniform h slice base, hoisted to SGPRs (readfirstlane)
    const uint64_t hp_u = (uint64_t)(uintptr_t)(h2g + (size_t)b * H_ + col0);
    const uint32_t hp_lo = __builtin_amdgcn_readfirstlane((uint32_t)hp_u);
    const uint32_t hp_hi = __builtin_amdgcn_readfirstlane((uint32_t)(hp_u >> 32));
    const uint64_t hp_s = ((uint64_t)hp_hi << 32) | hp_lo;

    __syncthreads();   // drains vmcnt -> h2g zeros visible to s_load below

    for (int t = 0; t < T_; ++t) {
        const int tn = (t < T_ - 1) ? t + 1 : t;
        const float s_nxt = sensH[((size_t)tn * B_ + b) * H_ + tid];
        const float a_nxt = acoef[(size_t)tn * H_ + tid];

        v16i h0, h1, h2, h3;
        asm volatile(
            "s_dcache_inv\n\t"
            "s_load_dwordx16 %0, %4, 0x0\n\t"
            "s_load_dwordx16 %1, %4, 0x40\n\t"
            "s_load_dwordx16 %2, %4, 0x80\n\t"
            "s_load_dwordx16 %3, %4, 0xc0\n\t"
            "s_waitcnt lgkmcnt(0)"
            : "=s"(h0), "=s"(h1), "=s"(h2), "=s"(h3)
            : "s"(hp_s));

        float acc[4] = {0.f, 0.f, 0.f, 0.f};
#pragma unroll
        for (int r = 0; r < 4; ++r) {
            // LDS tail for this row (4 x b128), issued ahead of consumption
            const float4 wv0 = *(const float4*)(wl + ((size_t)(r * 4 + 0) * 512 + tid) * 4);
            const float4 wv1 = *(const float4*)(wl + ((size_t)(r * 4 + 1) * 512 + tid) * 4);
            const float4 wv2 = *(const float4*)(wl + ((size_t)(r * 4 + 2) * 512 + tid) * 4);
            const float4 wv3 = *(const float4*)(wl + ((size_t)(r * 4 + 3) * 512 + tid) * 4);
#pragma unroll
            for (int k = 0; k < 48; ++k) DOT2SV(acc[r], HV(k), wr[r][k]);
            DOT2SV(acc[r], HV(48), as_h2(wv0.x));
            DOT2SV(acc[r], HV(49), as_h2(wv0.y));
            DOT2SV(acc[r], HV(50), as_h2(wv0.z));
            DOT2SV(acc[r], HV(51), as_h2(wv0.w));
            DOT2SV(acc[r], HV(52), as_h2(wv1.x));
            DOT2SV(acc[r], HV(53), as_h2(wv1.y));
            DOT2SV(acc[r], HV(54), as_h2(wv1.z));
            DOT2SV(acc[r], HV(55), as_h2(wv1.w));
            DOT2SV(acc[r], HV(56), as_h2(wv2.x));
            DOT2SV(acc[r], HV(57), as_h2(wv2.y));
            DOT2SV(acc[r], HV(58), as_h2(wv2.z));
            DOT2SV(acc[r], HV(59), as_h2(wv2.w));
            DOT2SV(acc[r], HV(60), as_h2(wv3.x));
            DOT2SV(acc[r], HV(61), as_h2(wv3.y));
            DOT2SV(acc[r], HV(62), as_h2(wv3.z));
            DOT2SV(acc[r], HV(63), as_h2(wv3.w));
        }
        *(float4*)(pred + cw * 512 + row0) =
            make_float4(acc[0], acc[1], acc[2], acc[3]);
        __syncthreads();

        // update phase: thread owns h[tid]
        {
            const float rec = pred[tid] + pred[512 + tid] +
                              pred[1024 + tid] + pred[1536 + tid];
            const float act = tanhf(s_cur + rec + bias_r);
            h_reg = a_cur * h_reg + DT_ * act;
            sensH[((size_t)t * B_ + b) * H_ + tid] = h_reg;   // hiddens for K4
            h2g[(size_t)b * H_ + tid] = (_Float16)h_reg;      // next step's h
            s_cur = s_nxt;
            a_cur = a_nxt;
        }
        __syncthreads();   // drains vmcnt -> h2g stores visible to next s_load
    }
    finalh[(size_t)b * H_ + tid] = h_reg;
}

// ---------------------------------------------------------------------------
extern "C" void kernel_launch(void* const* d_in, const int* in_sizes, int n_in,
                              void* d_out, int out_size, void* d_ws, size_t ws_size,
                              hipStream_t stream) {
    const float* x    = (const float*)d_in[0];
    const float* Win  = (const float*)d_in[1];
    const float* Wr   = (const float*)d_in[2];
    const float* tc   = (const float*)d_in[3];
    const float* Wo   = (const float*)d_in[4];
    const float* bias = (const float*)d_in[5];
    float* out = (float*)d_out;

    float* sensH = (float*)d_ws;                               // [T*B][H], later hiddens
    float* acoef = sensH + (size_t)T_ * B_ * H_;               // [T][H]
    const size_t need = ((size_t)T_ * B_ * H_ + (size_t)T_ * H_) * sizeof(float);
    if (ws_size < need) return;

    // h scratch (1 KB f16 per batch) at the head of d_out; K4 overwrites it.
    _Float16* h2g = (_Float16*)d_out;

    (void)hipFuncSetAttribute((const void*)scan_kernel,
                              hipFuncAttributeMaxDynamicSharedMemorySize, SMEM_TOT);

    // K1: sensory[t*32+b][h] = sum_i x[b][t][i] * Win[h][i]
    {
        dim3 grid(32768 / 128, H_ / 128);
        hipLaunchKernelGGL((gemm128<H_, IN_, true, false>), grid, dim3(256), 0, stream,
                           x, Win, sensH);
    }
    // K2: a_coef
    hipLaunchKernelGGL(tau_kernel, dim3(T_), dim3(H_), 0, stream, sensH, tc, acoef);
    // K3: scan
    hipLaunchKernelGGL(scan_kernel, dim3(B_), dim3(512), SMEM_TOT, stream,
                       Wr, acoef, bias, sensH, out + (size_t)B_ * T_ * O_, h2g);
    // K4: out[b][t][o] = sum_h hiddens[t*32+b][h] * Wo[o][h]
    {
        dim3 grid(32768 / 128, O_ / 128);
        hipLaunchKernelGGL((gemm128<O_, H_, false, true>), grid, dim3(256), 0, stream,
                           sensH, Wo, out);
    }
}

// Round 7
// 1798.146 us; speedup vs baseline: 2.2120x; 1.0518x over previous
//
#include <hip/hip_runtime.h>
#include <cstddef>
#include <cstdint>

#define B_ 32
#define T_ 1024
#define IN_ 256
#define H_ 512
#define O_ 256
#define DT_ 0.1f

typedef _Float16 half2_t __attribute__((ext_vector_type(2)));

__device__ __forceinline__ float fdot2(half2_t a, half2_t b, float c) {
    return __builtin_amdgcn_fdot2(a, b, c, false);
}
__device__ __forceinline__ half2_t cvt2(float x, float y) {
    half2_t r; r[0] = (_Float16)x; r[1] = (_Float16)y; return r;
}
__device__ __forceinline__ half2_t as_h2(float f) {
    union { float f; half2_t h; } u; u.f = f; return u.h;
}

// ---------------------------------------------------------------------------
// Generic fp32 GEMM: C[m][n] = sum_k A[m][k] * Bw[n][k],  M = 32768 fixed.
// ---------------------------------------------------------------------------
template<int N, int K, bool SWA, bool SWC>
__global__ __launch_bounds__(256, 4) void gemm128(const float* __restrict__ A,
                                                  const float* __restrict__ Bw,
                                                  float* __restrict__ C) {
    __shared__ float al[32][132];
    __shared__ float bl[32][132];
    const int tid = threadIdx.x;
    const int m0 = blockIdx.x * 128;
    const int n0 = blockIdx.y * 128;
    const int tx = tid & 15;
    const int ty = tid >> 4;
    float acc[8][8] = {};

    const int lrow = tid >> 3;
    const int kk = (tid & 7) * 4;

    for (int kc = 0; kc < K; kc += 32) {
        __syncthreads();
#pragma unroll
        for (int p = 0; p < 4; ++p) {
            const int row = lrow + p * 32;
            const int m = m0 + row;
            const size_t aoff = SWA ? ((size_t)((m & 31) * T_ + (m >> 5)) * K)
                                    : ((size_t)m * K);
            const float4 v = *(const float4*)(A + aoff + kc + kk);
            al[kk + 0][row] = v.x; al[kk + 1][row] = v.y;
            al[kk + 2][row] = v.z; al[kk + 3][row] = v.w;
        }
#pragma unroll
        for (int p = 0; p < 4; ++p) {
            const int row = lrow + p * 32;
            const float4 v = *(const float4*)(Bw + (size_t)(n0 + row) * K + kc + kk);
            bl[kk + 0][row] = v.x; bl[kk + 1][row] = v.y;
            bl[kk + 2][row] = v.z; bl[kk + 3][row] = v.w;
        }
        __syncthreads();
#pragma unroll
        for (int k = 0; k < 32; ++k) {
            float av[8], bv[8];
            *(float4*)&av[0] = *(const float4*)&al[k][ty * 8];
            *(float4*)&av[4] = *(const float4*)&al[k][ty * 8 + 4];
            *(float4*)&bv[0] = *(const float4*)&bl[k][tx * 8];
            *(float4*)&bv[4] = *(const float4*)&bl[k][tx * 8 + 4];
#pragma unroll
            for (int i = 0; i < 8; ++i)
#pragma unroll
                for (int j = 0; j < 8; ++j)
                    acc[i][j] = fmaf(av[i], bv[j], acc[i][j]);
        }
    }
#pragma unroll
    for (int i = 0; i < 8; ++i) {
        const int m = m0 + ty * 8 + i;
        const size_t coff = SWC ? ((size_t)((m & 31) * T_ + (m >> 5)) * N)
                                : ((size_t)m * N);
        const float4 v0 = make_float4(acc[i][0], acc[i][1], acc[i][2], acc[i][3]);
        const float4 v1 = make_float4(acc[i][4], acc[i][5], acc[i][6], acc[i][7]);
        *(float4*)(C + coff + n0 + tx * 8) = v0;
        *(float4*)(C + coff + n0 + tx * 8 + 4) = v1;
    }
}

// ---------------------------------------------------------------------------
// K2: a_coef[t][h] = 1 - DT / softplus(tc[h] + 0.1 * mean_b |sensory[t][b][h]|)
// ---------------------------------------------------------------------------
__global__ __launch_bounds__(512) void tau_kernel(const float* __restrict__ sens,
                                                  const float* __restrict__ tc,
                                                  float* __restrict__ acoef) {
    const int t = blockIdx.x;
    const int h = threadIdx.x;
    float s = 0.f;
#pragma unroll 8
    for (int b = 0; b < B_; ++b)
        s += fabsf(sens[((size_t)t * B_ + b) * H_ + h]);
    const float x = tc[h] + 0.1f * (s * (1.f / 32.f));
    const float sp = fmaxf(x, 0.f) + log1pf(expf(-fabsf(x)));
    acoef[(size_t)t * H_ + h] = 1.f - DT_ / sp;
}

// ---------------------------------------------------------------------------
// K3: serial scan. 32 WGs (1/batch) x 512 threads (8 waves, 2/SIMD).
// Wave w: col-chunk cw = w&3 (128 cols), row-half rh = w>>2.
// Lane: rows rh*256 + lane*4 .. +3.
//   per row: 48 half2 (cols 0..95) in VGPRs (192 regs; num_vgpr(256) blocks
//            the 128V/128A unified-file split), 16 half2 (cols 96..127) in LDS
// h[512] f16 in LDS (uniform-broadcast b128 reads, cheap).
// Phase A dot2s are K-MAJOR across the 4 row chains: dependent ops on the
// same acc are 4 insts apart -> issue-bound, not latency-bound.
// Barriers are raw s_barrier + lgkmcnt(0) ONLY: the sensH global store is
// never drained inside the loop (no vmcnt at barriers; kernel-end drains it).
// ---------------------------------------------------------------------------
#define LDSW_BYTES (16 * 512 * 16)                       // 131072
#define SMEM_P     (4 * 512 * 4)                         // pred 8192
#define SMEM_TOT   (LDSW_BYTES + SMEM_P + 1024)          // + h2s = 140288

#define LW(r, p) (*(const float4*)(wl + ((size_t)((r) * 4 + (p)) * 512 + tid) * 4))
#define BARRIER_LGKM() asm volatile("s_waitcnt lgkmcnt(0)\n\ts_barrier" ::: "memory")

__global__ __attribute__((amdgpu_flat_work_group_size(512, 512),
                          amdgpu_waves_per_eu(2, 2), amdgpu_num_vgpr(256)))
void scan_kernel(const float* __restrict__ Wr, const float* __restrict__ acoef,
                 const float* __restrict__ bias, float* sensH,
                 float* __restrict__ finalh) {
    extern __shared__ char smem[];
    half2_t* wl   = (half2_t*)smem;                      // W tail [(r*4+p)*512+tid]*4+j
    float* pred   = (float*)(smem + LDSW_BYTES);         // [4][512]
    _Float16* h2s = (_Float16*)(smem + LDSW_BYTES + SMEM_P);   // [512]

    const int tid  = threadIdx.x;
    const int b    = blockIdx.x;
    const int lane = tid & 63;
    const int w    = tid >> 6;
    const int cw   = w & 3;
    const int rh   = w >> 2;
    const int row0 = rh * 256 + lane * 4;
    const int col0 = cw * 128;

    // --- one-time: W slice -> 192 VGPR half2 + 64 LDS half2 per lane ---
    half2_t wr[4][48];
#pragma unroll
    for (int r = 0; r < 4; ++r) {
        const float* wrow = Wr + (size_t)(row0 + r) * H_ + col0;
#pragma unroll
        for (int k = 0; k < 48; ++k) {
            const float2 v = *(const float2*)(wrow + 2 * k);
            wr[r][k] = cvt2(v.x, v.y);
        }
#pragma unroll
        for (int pp = 0; pp < 4; ++pp)
#pragma unroll
            for (int j = 0; j < 4; ++j) {
                const int k = 48 + pp * 4 + j;
                const float2 v = *(const float2*)(wrow + 2 * k);
                wl[((size_t)(r * 4 + pp) * 512 + tid) * 4 + j] = cvt2(v.x, v.y);
            }
    }

    if (tid < 256) ((half2_t*)h2s)[tid] = cvt2(0.f, 0.f);
    float h_reg = 0.f;
    const float bias_r = bias[tid];
    float s_cur = sensH[(size_t)b * H_ + tid];
    float a_cur = acoef[tid];
    __syncthreads();   // one-time full drain: wl + h2s visible

    const half2_t* h2c = (const half2_t*)h2s + cw * 64;  // wave-uniform base

    for (int t = 0; t < T_; ++t) {
        const int tn = (t < T_ - 1) ? t + 1 : t;
        const float s_nxt = sensH[((size_t)tn * B_ + b) * H_ + tid];
        const float a_nxt = acoef[(size_t)tn * H_ + tid];

        float acc[4]  = {0.f, 0.f, 0.f, 0.f};
        float accB[4] = {0.f, 0.f, 0.f, 0.f};

        // ---- phase A: k-major over 48 reg-resident cols, h in 8-half2 batches
        float4 hb0 = *(const float4*)(h2c + 0);
        float4 hb1 = *(const float4*)(h2c + 4);
#pragma unroll
        for (int bt = 0; bt < 6; ++bt) {
            const int nx = (bt < 5) ? 8 * (bt + 1) : 0;
            const float4 nb0 = *(const float4*)(h2c + nx);
            const float4 nb1 = *(const float4*)(h2c + nx + 4);
            const half2_t hh[8] = {as_h2(hb0.x), as_h2(hb0.y), as_h2(hb0.z), as_h2(hb0.w),
                                   as_h2(hb1.x), as_h2(hb1.y), as_h2(hb1.z), as_h2(hb1.w)};
#pragma unroll
            for (int j = 0; j < 8; ++j) {
                const int k = bt * 8 + j;
                acc[0] = fdot2(wr[0][k], hh[j], acc[0]);
                acc[1] = fdot2(wr[1][k], hh[j], acc[1]);
                acc[2] = fdot2(wr[2][k], hh[j], acc[2]);
                acc[3] = fdot2(wr[3][k], hh[j], acc[3]);
            }
            hb0 = nb0; hb1 = nb1;
        }

        // ---- phase B: LDS W-tail (16 b128), h tail 16 half2, 2 chains/row
        {
            const float4 t0 = *(const float4*)(h2c + 48);
            const float4 t1 = *(const float4*)(h2c + 52);
            const float4 t2 = *(const float4*)(h2c + 56);
            const float4 t3 = *(const float4*)(h2c + 60);
            const half2_t ht[16] = {as_h2(t0.x), as_h2(t0.y), as_h2(t0.z), as_h2(t0.w),
                                    as_h2(t1.x), as_h2(t1.y), as_h2(t1.z), as_h2(t1.w),
                                    as_h2(t2.x), as_h2(t2.y), as_h2(t2.z), as_h2(t2.w),
                                    as_h2(t3.x), as_h2(t3.y), as_h2(t3.z), as_h2(t3.w)};
#pragma unroll
            for (int r = 0; r < 4; ++r) {
                const float4 w0 = LW(r, 0), w1 = LW(r, 1);
                acc[r]  = fdot2(as_h2(w0.x), ht[0], acc[r]);
                accB[r] = fdot2(as_h2(w0.y), ht[1], accB[r]);
                acc[r]  = fdot2(as_h2(w0.z), ht[2], acc[r]);
                accB[r] = fdot2(as_h2(w0.w), ht[3], accB[r]);
                acc[r]  = fdot2(as_h2(w1.x), ht[4], acc[r]);
                accB[r] = fdot2(as_h2(w1.y), ht[5], accB[r]);
                acc[r]  = fdot2(as_h2(w1.z), ht[6], acc[r]);
                accB[r] = fdot2(as_h2(w1.w), ht[7], accB[r]);
                const float4 w2 = LW(r, 2), w3 = LW(r, 3);
                acc[r]  = fdot2(as_h2(w2.x), ht[8],  acc[r]);
                accB[r] = fdot2(as_h2(w2.y), ht[9],  accB[r]);
                acc[r]  = fdot2(as_h2(w2.z), ht[10], acc[r]);
                accB[r] = fdot2(as_h2(w2.w), ht[11], accB[r]);
                acc[r]  = fdot2(as_h2(w3.x), ht[12], acc[r]);
                accB[r] = fdot2(as_h2(w3.y), ht[13], accB[r]);
                acc[r]  = fdot2(as_h2(w3.z), ht[14], acc[r]);
                accB[r] = fdot2(as_h2(w3.w), ht[15], accB[r]);
            }
        }

        *(float4*)(pred + cw * 512 + row0) =
            make_float4(acc[0] + accB[0], acc[1] + accB[1],
                        acc[2] + accB[2], acc[3] + accB[3]);
        BARRIER_LGKM();   // pred visible; NO vmcnt drain

        // update phase: thread owns h[tid]
        {
            const float rec = pred[tid] + pred[512 + tid] +
                              pred[1024 + tid] + pred[1536 + tid];
            const float act = tanhf(s_cur + rec + bias_r);
            h_reg = a_cur * h_reg + DT_ * act;
            sensH[((size_t)t * B_ + b) * H_ + tid] = h_reg;  // stays in flight
            h2s[tid] = (_Float16)h_reg;                      // next step's h
            s_cur = s_nxt;
            a_cur = a_nxt;
        }
        BARRIER_LGKM();   // h2s write visible; sensH store NOT drained
    }
    finalh[(size_t)b * H_ + tid] = h_reg;
}

// ---------------------------------------------------------------------------
extern "C" void kernel_launch(void* const* d_in, const int* in_sizes, int n_in,
                              void* d_out, int out_size, void* d_ws, size_t ws_size,
                              hipStream_t stream) {
    const float* x    = (const float*)d_in[0];
    const float* Win  = (const float*)d_in[1];
    const float* Wr   = (const float*)d_in[2];
    const float* tc   = (const float*)d_in[3];
    const float* Wo   = (const float*)d_in[4];
    const float* bias = (const float*)d_in[5];
    float* out = (float*)d_out;

    float* sensH = (float*)d_ws;                               // [T*B][H], later hiddens
    float* acoef = sensH + (size_t)T_ * B_ * H_;               // [T][H]
    const size_t need = ((size_t)T_ * B_ * H_ + (size_t)T_ * H_) * sizeof(float);
    if (ws_size < need) return;

    (void)hipFuncSetAttribute((const void*)scan_kernel,
                              hipFuncAttributeMaxDynamicSharedMemorySize, SMEM_TOT);

    // K1: sensory[t*32+b][h] = sum_i x[b][t][i] * Win[h][i]
    {
        dim3 grid(32768 / 128, H_ / 128);
        hipLaunchKernelGGL((gemm128<H_, IN_, true, false>), grid, dim3(256), 0, stream,
                           x, Win, sensH);
    }
    // K2: a_coef
    hipLaunchKernelGGL(tau_kernel, dim3(T_), dim3(H_), 0, stream, sensH, tc, acoef);
    // K3: scan
    hipLaunchKernelGGL(scan_kernel, dim3(B_), dim3(512), SMEM_TOT, stream,
                       Wr, acoef, bias, sensH, out + (size_t)B_ * T_ * O_);
    // K4: out[b][t][o] = sum_h hiddens[t*32+b][h] * Wo[o][h]
    {
        dim3 grid(32768 / 128, O_ / 128);
        hipLaunchKernelGGL((gemm128<O_, H_, false, true>), grid, dim3(256), 0, stream,
                           sensH, Wo, out);
    }
}